// Round 1
// baseline (2638.228 us; speedup 1.0000x reference)
//
#include <hip/hip_runtime.h>
#include <hip/hip_bf16.h>

// Problem dims (from reference)
#define D_IN  1024
#define HID   256
#define OUT_D 128

// ---------------------------------------------------------------------------
// Tiled f32 GEMM: C[M,N] = (relu?)(A[M,K] @ W[K,N] + bias[N])
// BM=64, BN=64, BK=16, 256 threads, 4x4 micro-tile per thread.
// N, K must be multiples of 64/16 (true for all calls here); M is bounds-checked.
// ---------------------------------------------------------------------------
template <bool RELU>
__global__ __launch_bounds__(256) void gemm_bias(
    const float* __restrict__ A, const float* __restrict__ W,
    const float* __restrict__ bias, float* __restrict__ C,
    int M, int N, int K)
{
    __shared__ float As[16][68];  // [k][m], padded
    __shared__ float Ws[16][64];  // [k][n]

    const int m0 = blockIdx.x * 64;
    const int n0 = blockIdx.y * 64;
    const int tid = threadIdx.x;
    const int tm = tid >> 4;   // 0..15 -> rows tm*4..tm*4+3
    const int tn = tid & 15;   // 0..15 -> cols tn*4..tn*4+3

    float acc[4][4] = {};

    for (int k0 = 0; k0 < K; k0 += 16) {
        // Load A tile (64 x 16): consecutive tids read consecutive k within a row
#pragma unroll
        for (int q = 0; q < 4; ++q) {
            int f = tid + 256 * q;
            int r = f >> 4, c = f & 15;
            int gm = m0 + r;
            As[c][r] = (gm < M) ? A[(size_t)gm * K + (k0 + c)] : 0.f;
        }
        // Load W tile (16 x 64): coalesced
#pragma unroll
        for (int q = 0; q < 4; ++q) {
            int f = tid + 256 * q;
            int r = f >> 6, c = f & 63;
            Ws[r][c] = W[(size_t)(k0 + r) * N + (n0 + c)];
        }
        __syncthreads();

#pragma unroll
        for (int k = 0; k < 16; ++k) {
            float a[4], w[4];
#pragma unroll
            for (int i = 0; i < 4; ++i) a[i] = As[k][tm * 4 + i];
#pragma unroll
            for (int j = 0; j < 4; ++j) w[j] = Ws[k][tn * 4 + j];
#pragma unroll
            for (int i = 0; i < 4; ++i)
#pragma unroll
                for (int j = 0; j < 4; ++j)
                    acc[i][j] += a[i] * w[j];
        }
        __syncthreads();
    }

#pragma unroll
    for (int i = 0; i < 4; ++i) {
        int gm = m0 + tm * 4 + i;
        if (gm >= M) continue;
#pragma unroll
        for (int j = 0; j < 4; ++j) {
            int gn = n0 + tn * 4 + j;
            float v = acc[i][j] + bias[gn];
            if (RELU) v = fmaxf(v, 0.f);
            C[(size_t)gm * N + gn] = v;
        }
    }
}

// ---------------------------------------------------------------------------
// Edge scatter-add: acc[dst[e], :] += msg[src[e], :]   (H = 256 floats/row)
// One 64-thread block per edge; float4 gather, 4 scalar atomics per thread.
// ---------------------------------------------------------------------------
__global__ __launch_bounds__(64) void scatter_add_edges(
    const float* __restrict__ msg, const int* __restrict__ src_idx,
    const int* __restrict__ dst_idx, float* __restrict__ acc, int nEdges)
{
    int e = blockIdx.x;
    if (e >= nEdges) return;
    int s = src_idx[e];
    int d = dst_idx[e];
    const float4* m = reinterpret_cast<const float4*>(msg + (size_t)s * HID);
    float* a = acc + (size_t)d * HID;
    int t = threadIdx.x;  // 0..63, covers 256 floats as float4
    float4 v = m[t];
    atomicAdd(a + 4 * t + 0, v.x);
    atomicAdd(a + 4 * t + 1, v.y);
    atomicAdd(a + 4 * t + 2, v.z);
    atomicAdd(a + 4 * t + 3, v.w);
}

extern "C" void kernel_launch(void* const* d_in, const int* in_sizes, int n_in,
                              void* d_out, int out_size, void* d_ws, size_t ws_size,
                              hipStream_t stream)
{
    const float* user_feat = (const float*)d_in[0];
    const float* dish_feat = (const float*)d_in[1];
    const int*   edge_user = (const int*)d_in[2];
    const int*   edge_dish = (const int*)d_in[3];
    const float* W_ui = (const float*)d_in[4];  const float* b_ui = (const float*)d_in[5];
    const float* W_di = (const float*)d_in[6];  const float* b_di = (const float*)d_in[7];
    const float* W_um = (const float*)d_in[8];  const float* b_um = (const float*)d_in[9];
    const float* W_dm = (const float*)d_in[10]; const float* b_dm = (const float*)d_in[11];
    const float* W_uu = (const float*)d_in[12]; const float* b_uu = (const float*)d_in[13];
    const float* W_du = (const float*)d_in[14]; const float* b_du = (const float*)d_in[15];
    const float* W_up = (const float*)d_in[16]; const float* b_up = (const float*)d_in[17];
    const float* W_dp = (const float*)d_in[18]; const float* b_dp = (const float*)d_in[19];

    const int U = in_sizes[0] / D_IN;   // 50000
    const int D = in_sizes[1] / D_IN;   // 10000
    const int E = in_sizes[2];          // 200000

    float* out = (float*)d_out;
    float* user_emb = out;                       // [U, OUT_D]
    float* dish_emb = out + (size_t)U * OUT_D;   // [D, OUT_D]

    // Workspace layout (floats)
    float* ws = (float*)d_ws;
    float* user_acc = ws;                               // [U, HID]  init -> init+agg
    float* user_msg = user_acc + (size_t)U * HID;       // [U, HID]  later reused as user_upd
    float* dish_acc = user_msg + (size_t)U * HID;       // [D, HID]
    float* dish_msg = dish_acc + (size_t)D * HID;       // [D, HID]  later reused as dish_upd

    dim3 blk(256);
    auto grid_for = [](int M, int N) { return dim3((M + 63) / 64, N / 64); };

    // 1-4: projections (user_acc = user_init, dish_acc = dish_init,
    //       *_msg = per-node message tables; gather commutes with matmul+relu)
    hipLaunchKernelGGL((gemm_bias<true>), grid_for(U, HID), blk, 0, stream,
                       user_feat, W_ui, b_ui, user_acc, U, HID, D_IN);
    hipLaunchKernelGGL((gemm_bias<true>), grid_for(U, HID), blk, 0, stream,
                       user_feat, W_dm, b_dm, user_msg, U, HID, D_IN);
    hipLaunchKernelGGL((gemm_bias<true>), grid_for(D, HID), blk, 0, stream,
                       dish_feat, W_di, b_di, dish_acc, D, HID, D_IN);
    hipLaunchKernelGGL((gemm_bias<true>), grid_for(D, HID), blk, 0, stream,
                       dish_feat, W_um, b_um, dish_msg, D, HID, D_IN);

    // 5-6: edge aggregation (acc already holds the *_init term)
    hipLaunchKernelGGL(scatter_add_edges, dim3(E), dim3(64), 0, stream,
                       dish_msg, edge_dish, edge_user, user_acc, E);
    hipLaunchKernelGGL(scatter_add_edges, dim3(E), dim3(64), 0, stream,
                       user_msg, edge_user, edge_dish, dish_acc, E);

    // 7-8: user update + projection (user_upd overwrites user_msg)
    float* user_upd = user_msg;
    hipLaunchKernelGGL((gemm_bias<true>), grid_for(U, HID), blk, 0, stream,
                       user_acc, W_uu, b_uu, user_upd, U, HID, HID);
    hipLaunchKernelGGL((gemm_bias<false>), grid_for(U, OUT_D), blk, 0, stream,
                       user_upd, W_up, b_up, user_emb, U, OUT_D, HID);

    // 9-10: dish update + projection (dish_upd overwrites dish_msg)
    float* dish_upd = dish_msg;
    hipLaunchKernelGGL((gemm_bias<true>), grid_for(D, HID), blk, 0, stream,
                       dish_acc, W_du, b_du, dish_upd, D, HID, HID);
    hipLaunchKernelGGL((gemm_bias<false>), grid_for(D, OUT_D), blk, 0, stream,
                       dish_upd, W_dp, b_dp, dish_emb, D, OUT_D, HID);
}

// Round 2
// 1490.500 us; speedup vs baseline: 1.7700x; 1.7700x over previous
//
#include <hip/hip_runtime.h>
#include <hip/hip_bf16.h>

// Problem dims (from reference)
#define D_IN  1024
#define HID   256
#define OUT_D 128

// ---------------------------------------------------------------------------
// Tiled f32 GEMM: C[M,N] = (relu?)(A[M,K] @ W[K,N] + bias[N])
// BM=64, BN=64, BK=16, 256 threads, 4x4 micro-tile per thread.
// ---------------------------------------------------------------------------
template <bool RELU>
__global__ __launch_bounds__(256) void gemm_bias(
    const float* __restrict__ A, const float* __restrict__ W,
    const float* __restrict__ bias, float* __restrict__ C,
    int M, int N, int K)
{
    __shared__ float As[16][68];  // [k][m], padded
    __shared__ float Ws[16][64];  // [k][n]

    const int m0 = blockIdx.x * 64;
    const int n0 = blockIdx.y * 64;
    const int tid = threadIdx.x;
    const int tm = tid >> 4;
    const int tn = tid & 15;

    float acc[4][4] = {};

    for (int k0 = 0; k0 < K; k0 += 16) {
#pragma unroll
        for (int q = 0; q < 4; ++q) {
            int f = tid + 256 * q;
            int r = f >> 4, c = f & 15;
            int gm = m0 + r;
            As[c][r] = (gm < M) ? A[(size_t)gm * K + (k0 + c)] : 0.f;
        }
#pragma unroll
        for (int q = 0; q < 4; ++q) {
            int f = tid + 256 * q;
            int r = f >> 6, c = f & 63;
            Ws[r][c] = W[(size_t)(k0 + r) * N + (n0 + c)];
        }
        __syncthreads();

#pragma unroll
        for (int k = 0; k < 16; ++k) {
            float a[4], w[4];
#pragma unroll
            for (int i = 0; i < 4; ++i) a[i] = As[k][tm * 4 + i];
#pragma unroll
            for (int j = 0; j < 4; ++j) w[j] = Ws[k][tn * 4 + j];
#pragma unroll
            for (int i = 0; i < 4; ++i)
#pragma unroll
                for (int j = 0; j < 4; ++j)
                    acc[i][j] += a[i] * w[j];
        }
        __syncthreads();
    }

#pragma unroll
    for (int i = 0; i < 4; ++i) {
        int gm = m0 + tm * 4 + i;
        if (gm >= M) continue;
#pragma unroll
        for (int j = 0; j < 4; ++j) {
            int gn = n0 + tn * 4 + j;
            float v = acc[i][j] + bias[gn];
            if (RELU) v = fmaxf(v, 0.f);
            C[(size_t)gm * N + gn] = v;
        }
    }
}

// ---------------------------------------------------------------------------
// CSR construction: histogram -> single-block scan -> fill (int atomics only)
// ---------------------------------------------------------------------------
__global__ void hist_kernel(const int* __restrict__ dst, int* __restrict__ cnt, int n)
{
    int i = blockIdx.x * blockDim.x + threadIdx.x;
    if (i < n) atomicAdd(&cnt[dst[i]], 1);
}

// Exclusive scan of cnt[0..n) -> offs[0..n), single block of 1024 threads.
__global__ __launch_bounds__(1024) void scan_kernel(
    const int* __restrict__ cnt, int* __restrict__ offs, int n)
{
    __shared__ int tsum[1024];
    const int t = threadIdx.x;
    const int chunk = (n + 1023) / 1024;
    const int lo = t * chunk;
    const int hi = min(lo + chunk, n);
    int s = 0;
    for (int i = lo; i < hi; ++i) s += cnt[i];
    tsum[t] = s;
    __syncthreads();
    for (int d = 1; d < 1024; d <<= 1) {
        int v = (t >= d) ? tsum[t - d] : 0;
        __syncthreads();
        tsum[t] += v;
        __syncthreads();
    }
    int run = (t > 0) ? tsum[t - 1] : 0;  // exclusive prefix at chunk start
    for (int i = lo; i < hi; ++i) {
        offs[i] = run;
        run += cnt[i];
    }
}

// srclist[pos] = src[e], grouped by dst. Mutates offs: afterwards offs[i] = segment END.
__global__ void fill_kernel(const int* __restrict__ dst, const int* __restrict__ src,
                            int* __restrict__ offs, int* __restrict__ srclist, int n)
{
    int i = blockIdx.x * blockDim.x + threadIdx.x;
    if (i < n) {
        int p = atomicAdd(&offs[dst[i]], 1);
        srclist[p] = src[i];
    }
}

// ---------------------------------------------------------------------------
// Segment sum: acc[row,:] += sum_{j in seg(row)} msg[srclist[j], :]
// One 64-lane wave per row (HID=256 floats = 64 lanes x float4).
// offs_end[row] = segment end (post-fill), cnt[row] = degree.
// ---------------------------------------------------------------------------
__global__ __launch_bounds__(256) void seg_sum(
    const float* __restrict__ msg, const int* __restrict__ srclist,
    const int* __restrict__ offs_end, const int* __restrict__ cnt,
    float* __restrict__ acc, int nRows)
{
    int row = blockIdx.x * 4 + (threadIdx.x >> 6);
    if (row >= nRows) return;
    const int lane = threadIdx.x & 63;
    const int deg = cnt[row];
    if (deg == 0) return;
    const int base = offs_end[row] - deg;

    float4 sum = make_float4(0.f, 0.f, 0.f, 0.f);
    int j = 0;
    for (; j + 1 < deg; j += 2) {
        int s0 = srclist[base + j];
        int s1 = srclist[base + j + 1];
        float4 v0 = reinterpret_cast<const float4*>(msg + (size_t)s0 * HID)[lane];
        float4 v1 = reinterpret_cast<const float4*>(msg + (size_t)s1 * HID)[lane];
        sum.x += v0.x; sum.y += v0.y; sum.z += v0.z; sum.w += v0.w;
        sum.x += v1.x; sum.y += v1.y; sum.z += v1.z; sum.w += v1.w;
    }
    if (j < deg) {
        int s0 = srclist[base + j];
        float4 v0 = reinterpret_cast<const float4*>(msg + (size_t)s0 * HID)[lane];
        sum.x += v0.x; sum.y += v0.y; sum.z += v0.z; sum.w += v0.w;
    }

    float4* a = reinterpret_cast<float4*>(acc + (size_t)row * HID) + lane;
    float4 c = *a;
    c.x += sum.x; c.y += sum.y; c.z += sum.z; c.w += sum.w;
    *a = c;
}

extern "C" void kernel_launch(void* const* d_in, const int* in_sizes, int n_in,
                              void* d_out, int out_size, void* d_ws, size_t ws_size,
                              hipStream_t stream)
{
    const float* user_feat = (const float*)d_in[0];
    const float* dish_feat = (const float*)d_in[1];
    const int*   edge_user = (const int*)d_in[2];
    const int*   edge_dish = (const int*)d_in[3];
    const float* W_ui = (const float*)d_in[4];  const float* b_ui = (const float*)d_in[5];
    const float* W_di = (const float*)d_in[6];  const float* b_di = (const float*)d_in[7];
    const float* W_um = (const float*)d_in[8];  const float* b_um = (const float*)d_in[9];
    const float* W_dm = (const float*)d_in[10]; const float* b_dm = (const float*)d_in[11];
    const float* W_uu = (const float*)d_in[12]; const float* b_uu = (const float*)d_in[13];
    const float* W_du = (const float*)d_in[14]; const float* b_du = (const float*)d_in[15];
    const float* W_up = (const float*)d_in[16]; const float* b_up = (const float*)d_in[17];
    const float* W_dp = (const float*)d_in[18]; const float* b_dp = (const float*)d_in[19];

    const int U = in_sizes[0] / D_IN;   // 50000
    const int D = in_sizes[1] / D_IN;   // 10000
    const int E = in_sizes[2];          // 200000

    float* out = (float*)d_out;
    float* user_emb = out;                       // [U, OUT_D]
    float* dish_emb = out + (size_t)U * OUT_D;   // [D, OUT_D]

    // Workspace layout
    float* ws = (float*)d_ws;
    float* user_acc = ws;                               // [U, HID]
    float* user_msg = user_acc + (size_t)U * HID;       // [U, HID]  later user_upd
    float* dish_acc = user_msg + (size_t)U * HID;       // [D, HID]
    float* dish_msg = dish_acc + (size_t)D * HID;       // [D, HID]  later dish_upd
    int*   iws      = (int*)(dish_msg + (size_t)D * HID);
    int* cnt_u  = iws;                 // [U]
    int* offs_u = cnt_u + U;           // [U]
    int* cnt_d  = offs_u + U;          // [D]
    int* offs_d = cnt_d + D;           // [D]
    int* srcl_u = offs_d + D;          // [E] dish indices grouped by user
    int* srcl_d = srcl_u + E;          // [E] user indices grouped by dish

    dim3 blk(256);
    auto grid_for = [](int M, int N) { return dim3((M + 63) / 64, N / 64); };

    // 1-4: projections
    hipLaunchKernelGGL((gemm_bias<true>), grid_for(U, HID), blk, 0, stream,
                       user_feat, W_ui, b_ui, user_acc, U, HID, D_IN);
    hipLaunchKernelGGL((gemm_bias<true>), grid_for(U, HID), blk, 0, stream,
                       user_feat, W_dm, b_dm, user_msg, U, HID, D_IN);
    hipLaunchKernelGGL((gemm_bias<true>), grid_for(D, HID), blk, 0, stream,
                       dish_feat, W_di, b_di, dish_acc, D, HID, D_IN);
    hipLaunchKernelGGL((gemm_bias<true>), grid_for(D, HID), blk, 0, stream,
                       dish_feat, W_um, b_um, dish_msg, D, HID, D_IN);

    // CSR build for both directions (int atomics only)
    hipMemsetAsync(cnt_u, 0, (size_t)U * sizeof(int), stream);
    hipMemsetAsync(cnt_d, 0, (size_t)D * sizeof(int), stream);
    int egrid = (E + 255) / 256;
    hipLaunchKernelGGL(hist_kernel, dim3(egrid), blk, 0, stream, edge_user, cnt_u, E);
    hipLaunchKernelGGL(hist_kernel, dim3(egrid), blk, 0, stream, edge_dish, cnt_d, E);
    hipLaunchKernelGGL(scan_kernel, dim3(1), dim3(1024), 0, stream, cnt_u, offs_u, U);
    hipLaunchKernelGGL(scan_kernel, dim3(1), dim3(1024), 0, stream, cnt_d, offs_d, D);
    hipLaunchKernelGGL(fill_kernel, dim3(egrid), blk, 0, stream,
                       edge_user, edge_dish, offs_u, srcl_u, E);
    hipLaunchKernelGGL(fill_kernel, dim3(egrid), blk, 0, stream,
                       edge_dish, edge_user, offs_d, srcl_d, E);

    // 5-6: aggregation via gather segment-sum (acc already holds *_init)
    hipLaunchKernelGGL(seg_sum, dim3((U + 3) / 4), blk, 0, stream,
                       dish_msg, srcl_u, offs_u, cnt_u, user_acc, U);
    hipLaunchKernelGGL(seg_sum, dim3((D + 3) / 4), blk, 0, stream,
                       user_msg, srcl_d, offs_d, cnt_d, dish_acc, D);

    // 7-8: user update + projection
    float* user_upd = user_msg;
    hipLaunchKernelGGL((gemm_bias<true>), grid_for(U, HID), blk, 0, stream,
                       user_acc, W_uu, b_uu, user_upd, U, HID, HID);
    hipLaunchKernelGGL((gemm_bias<false>), grid_for(U, OUT_D), blk, 0, stream,
                       user_upd, W_up, b_up, user_emb, U, OUT_D, HID);

    // 9-10: dish update + projection
    float* dish_upd = dish_msg;
    hipLaunchKernelGGL((gemm_bias<true>), grid_for(D, HID), blk, 0, stream,
                       dish_acc, W_du, b_du, dish_upd, D, HID, HID);
    hipLaunchKernelGGL((gemm_bias<false>), grid_for(D, OUT_D), blk, 0, stream,
                       dish_upd, W_dp, b_dp, dish_emb, D, OUT_D, HID);
}

// Round 3
// 673.222 us; speedup vs baseline: 3.9188x; 2.2140x over previous
//
#include <hip/hip_runtime.h>
#include <hip/hip_bf16.h>

// Problem dims
#define D_IN  1024
#define HID   256
#define OUT_D 128

using bf16x8  = __attribute__((ext_vector_type(8))) short;   // 8 bf16
using bf16x4  = __attribute__((ext_vector_type(4))) short;   // 4 bf16
using f32x4   = __attribute__((ext_vector_type(4))) float;

__device__ inline float bf2f(short s) {
    unsigned u = ((unsigned)(unsigned short)s) << 16;
    return __uint_as_float(u);
}
__device__ inline short f2bf(float f) {
    __hip_bfloat16 h = __float2bfloat16(f);   // RNE
    return *reinterpret_cast<short*>(&h);
}

// ---------------------------------------------------------------------------
// Weight pack: in f32 [K][N] -> out bf16 [n_off+n][K] (transposed, row=n).
// grid (N/32, K/32), block (32,8).
// ---------------------------------------------------------------------------
__global__ void transpose_pack(const float* __restrict__ in, short* __restrict__ out,
                               int K, int N, int n_off)
{
    __shared__ float t[32][33];
    const int n0 = blockIdx.x * 32, k0 = blockIdx.y * 32;
    const int tx = threadIdx.x, ty = threadIdx.y;
#pragma unroll
    for (int j = 0; j < 32; j += 8)
        t[ty + j][tx] = in[(size_t)(k0 + ty + j) * N + (n0 + tx)];
    __syncthreads();
#pragma unroll
    for (int j = 0; j < 32; j += 8)
        out[(size_t)(n_off + n0 + ty + j) * K + (k0 + tx)] = f2bf(t[tx][ty + j]);
}

__global__ void concat2(const float* __restrict__ a, const float* __restrict__ b,
                        float* __restrict__ out, int na, int nb)
{
    int i = blockIdx.x * blockDim.x + threadIdx.x;
    if (i < na) out[i] = a[i];
    else if (i < na + nb) out[i] = b[i - na];
}

// ---------------------------------------------------------------------------
// MFMA GEMM: C[M,N] = (relu?)(A[M,K] @ W[K,N] + bias), W given as Wt[N][K] bf16.
// BM=BN=128, BK=32, 256 threads (4 waves, 2x2), wave tile 64x64 = 4x4 frags
// of v_mfma_f32_16x16x32_bf16. A is f32 (converted in staging) or bf16.
// LDS rows padded to 40 shorts (80 B) -> 2-way bank aliasing (free).
// ---------------------------------------------------------------------------
template <bool RELU, bool AF32, bool CF32>
__global__ __launch_bounds__(256) void mfma_gemm(
    const void* __restrict__ Avoid, int lda,
    const short* __restrict__ Wt,
    const float* __restrict__ bias,
    void* __restrict__ Cvoid, int M, int N, int K)
{
    __shared__ __align__(16) short As[128 * 40];
    __shared__ __align__(16) short Bs[128 * 40];

    const int tid = threadIdx.x;
    const int n0 = blockIdx.x * 128;
    const int m0 = blockIdx.y * 128;
    const int w  = tid >> 6, l = tid & 63;
    const int wm = (w >> 1) * 64, wn = (w & 1) * 64;
    const int fr = l & 15;        // fragment row/col index
    const int fg = l >> 4;        // k-group (0..3)

    f32x4 acc[4][4] = {};

    for (int k0 = 0; k0 < K; k0 += 32) {
        // ---- stage A tile (128 x 32) ----
        if (AF32) {
            const float* A = (const float*)Avoid;
#pragma unroll
            for (int p = 0; p < 4; ++p) {
                int id = tid + 256 * p;
                int r = id >> 3, c = (id & 7) * 4;
                int gm = m0 + r;
                float4 v = (gm < M) ? *(const float4*)&A[(size_t)gm * lda + k0 + c]
                                    : make_float4(0.f, 0.f, 0.f, 0.f);
                bf16x4 s;
                s[0] = f2bf(v.x); s[1] = f2bf(v.y); s[2] = f2bf(v.z); s[3] = f2bf(v.w);
                *(bf16x4*)&As[r * 40 + c] = s;
            }
        } else {
            const short* A = (const short*)Avoid;
#pragma unroll
            for (int p = 0; p < 2; ++p) {
                int id = tid + 256 * p;
                int r = id >> 2, c = (id & 3) * 8;
                int gm = m0 + r;
                bf16x8 v = {};
                if (gm < M) v = *(const bf16x8*)&A[(size_t)gm * lda + k0 + c];
                *(bf16x8*)&As[r * 40 + c] = v;
            }
        }
        // ---- stage B tile (Wt rows n0..n0+127, k0..k0+31); N % 128 == 0 ----
#pragma unroll
        for (int p = 0; p < 2; ++p) {
            int id = tid + 256 * p;
            int r = id >> 2, c = (id & 3) * 8;
            *(bf16x8*)&Bs[r * 40 + c] = *(const bf16x8*)&Wt[(size_t)(n0 + r) * K + k0 + c];
        }
        __syncthreads();

        bf16x8 af[4], bfr[4];
#pragma unroll
        for (int i = 0; i < 4; ++i)
            af[i] = *(bf16x8*)&As[(wm + i * 16 + fr) * 40 + fg * 8];
#pragma unroll
        for (int j = 0; j < 4; ++j)
            bfr[j] = *(bf16x8*)&Bs[(wn + j * 16 + fr) * 40 + fg * 8];
#pragma unroll
        for (int i = 0; i < 4; ++i)
#pragma unroll
            for (int j = 0; j < 4; ++j)
                acc[i][j] = __builtin_amdgcn_mfma_f32_16x16x32_bf16(
                    af[i], bfr[j], acc[i][j], 0, 0, 0);
        __syncthreads();
    }

    // epilogue: C/D layout col=lane&15, row=(lane>>4)*4+reg  [m89-verified]
#pragma unroll
    for (int i = 0; i < 4; ++i) {
#pragma unroll
        for (int q = 0; q < 4; ++q) {
            int gm = m0 + wm + i * 16 + fg * 4 + q;
            if (gm >= M) continue;
#pragma unroll
            for (int j = 0; j < 4; ++j) {
                int gn = n0 + wn + j * 16 + fr;
                float v = acc[i][j][q] + bias[gn];
                if (RELU) v = fmaxf(v, 0.f);
                if (CF32) ((float*)Cvoid)[(size_t)gm * N + gn] = v;
                else      ((short*)Cvoid)[(size_t)gm * N + gn] = f2bf(v);
            }
        }
    }
}

// ---------------------------------------------------------------------------
// CSR construction (int atomics only)
// ---------------------------------------------------------------------------
__global__ void hist_kernel(const int* __restrict__ dst, int* __restrict__ cnt, int n)
{
    int i = blockIdx.x * blockDim.x + threadIdx.x;
    if (i < n) atomicAdd(&cnt[dst[i]], 1);
}

__global__ __launch_bounds__(1024) void scan_kernel(
    const int* __restrict__ cnt, int* __restrict__ offs, int n)
{
    __shared__ int tsum[1024];
    const int t = threadIdx.x;
    const int chunk = (n + 1023) / 1024;
    const int lo = t * chunk;
    const int hi = min(lo + chunk, n);
    int s = 0;
    for (int i = lo; i < hi; ++i) s += cnt[i];
    tsum[t] = s;
    __syncthreads();
    for (int d = 1; d < 1024; d <<= 1) {
        int v = (t >= d) ? tsum[t - d] : 0;
        __syncthreads();
        tsum[t] += v;
        __syncthreads();
    }
    int run = (t > 0) ? tsum[t - 1] : 0;
    for (int i = lo; i < hi; ++i) {
        offs[i] = run;
        run += cnt[i];
    }
}

__global__ void fill_kernel(const int* __restrict__ dst, const int* __restrict__ src,
                            int* __restrict__ offs, int* __restrict__ srclist, int n)
{
    int i = blockIdx.x * blockDim.x + threadIdx.x;
    if (i < n) {
        int p = atomicAdd(&offs[dst[i]], 1);
        srclist[p] = src[i];
    }
}

// ---------------------------------------------------------------------------
// Segment sum (bf16): acc[row,:] += sum_j msg[srclist[j],:]; in-place on acc.
// One 64-lane wave per row; HID=256 bf16 = 64 lanes x bf16x4 (8 B).
// ---------------------------------------------------------------------------
__global__ __launch_bounds__(256) void seg_sum_bf16(
    const short* __restrict__ msg, int msg_ld,
    const int* __restrict__ srclist,
    const int* __restrict__ offs_end, const int* __restrict__ cnt,
    short* __restrict__ acc, int acc_ld, int nRows)
{
    int row = blockIdx.x * 4 + (threadIdx.x >> 6);
    if (row >= nRows) return;
    const int lane = threadIdx.x & 63;
    const int deg = cnt[row];
    if (deg == 0) return;
    const int base = offs_end[row] - deg;

    float s0 = 0.f, s1 = 0.f, s2 = 0.f, s3 = 0.f;
    for (int j = 0; j < deg; ++j) {
        int src = srclist[base + j];
        bf16x4 v = *(const bf16x4*)&msg[(size_t)src * msg_ld + lane * 4];
        s0 += bf2f(v[0]); s1 += bf2f(v[1]); s2 += bf2f(v[2]); s3 += bf2f(v[3]);
    }
    bf16x4 c = *(bf16x4*)&acc[(size_t)row * acc_ld + lane * 4];
    c[0] = f2bf(bf2f(c[0]) + s0);
    c[1] = f2bf(bf2f(c[1]) + s1);
    c[2] = f2bf(bf2f(c[2]) + s2);
    c[3] = f2bf(bf2f(c[3]) + s3);
    *(bf16x4*)&acc[(size_t)row * acc_ld + lane * 4] = c;
}

extern "C" void kernel_launch(void* const* d_in, const int* in_sizes, int n_in,
                              void* d_out, int out_size, void* d_ws, size_t ws_size,
                              hipStream_t stream)
{
    const float* user_feat = (const float*)d_in[0];
    const float* dish_feat = (const float*)d_in[1];
    const int*   edge_user = (const int*)d_in[2];
    const int*   edge_dish = (const int*)d_in[3];
    const float* W_ui = (const float*)d_in[4];  const float* b_ui = (const float*)d_in[5];
    const float* W_di = (const float*)d_in[6];  const float* b_di = (const float*)d_in[7];
    const float* W_um = (const float*)d_in[8];  const float* b_um = (const float*)d_in[9];
    const float* W_dm = (const float*)d_in[10]; const float* b_dm = (const float*)d_in[11];
    const float* W_uu = (const float*)d_in[12]; const float* b_uu = (const float*)d_in[13];
    const float* W_du = (const float*)d_in[14]; const float* b_du = (const float*)d_in[15];
    const float* W_up = (const float*)d_in[16]; const float* b_up = (const float*)d_in[17];
    const float* W_dp = (const float*)d_in[18]; const float* b_dp = (const float*)d_in[19];

    const int U = in_sizes[0] / D_IN;   // 50000
    const int D = in_sizes[1] / D_IN;   // 10000
    const int E = in_sizes[2];          // 200000

    float* out = (float*)d_out;
    float* user_emb = out;                       // [U, OUT_D] f32
    float* dish_emb = out + (size_t)U * OUT_D;   // [D, OUT_D] f32

    // ---- workspace layout (bf16 = short) ----
    short* sws = (short*)d_ws;
    short* user_buf = sws;                                  // [U][512]: init | msg
    short* dish_buf = user_buf + (size_t)U * 512;           // [D][512]: init | msg
    short* user_upd = dish_buf + (size_t)D * 512;           // [U][256]
    short* dish_upd = user_upd + (size_t)U * 256;           // [D][256]
    short* Wut  = dish_upd + (size_t)D * 256;               // [512][1024]
    short* Wdt  = Wut  + (size_t)512 * 1024;                // [512][1024]
    short* Wuut = Wdt  + (size_t)512 * 1024;                // [256][256]
    short* Wdut = Wuut + (size_t)256 * 256;                 // [256][256]
    short* Wupt = Wdut + (size_t)256 * 256;                 // [128][256]
    short* Wdpt = Wupt + (size_t)128 * 256;                 // [128][256]
    float* bu   = (float*)(Wdpt + (size_t)128 * 256);       // [512]
    float* bd   = bu + 512;                                 // [512]
    int*   cnt_u  = (int*)(bd + 512);                       // [U]
    int*   offs_u = cnt_u + U;
    int*   cnt_d  = offs_u + U;
    int*   offs_d = cnt_d + D;
    int*   srcl_u = offs_d + D;                             // [E]
    int*   srcl_d = srcl_u + E;                             // [E]

    // ---- pack weights (transpose to [n][k] bf16) + concat biases ----
    dim3 tb(32, 8);
    hipLaunchKernelGGL(transpose_pack, dim3(HID / 32, D_IN / 32), tb, 0, stream,
                       W_ui, Wut, D_IN, HID, 0);
    hipLaunchKernelGGL(transpose_pack, dim3(HID / 32, D_IN / 32), tb, 0, stream,
                       W_dm, Wut, D_IN, HID, HID);
    hipLaunchKernelGGL(transpose_pack, dim3(HID / 32, D_IN / 32), tb, 0, stream,
                       W_di, Wdt, D_IN, HID, 0);
    hipLaunchKernelGGL(transpose_pack, dim3(HID / 32, D_IN / 32), tb, 0, stream,
                       W_um, Wdt, D_IN, HID, HID);
    hipLaunchKernelGGL(transpose_pack, dim3(HID / 32, HID / 32), tb, 0, stream,
                       W_uu, Wuut, HID, HID, 0);
    hipLaunchKernelGGL(transpose_pack, dim3(HID / 32, HID / 32), tb, 0, stream,
                       W_du, Wdut, HID, HID, 0);
    hipLaunchKernelGGL(transpose_pack, dim3(OUT_D / 32, HID / 32), tb, 0, stream,
                       W_up, Wupt, HID, OUT_D, 0);
    hipLaunchKernelGGL(transpose_pack, dim3(OUT_D / 32, HID / 32), tb, 0, stream,
                       W_dp, Wdpt, HID, OUT_D, 0);
    hipLaunchKernelGGL(concat2, dim3(2), dim3(256), 0, stream, b_ui, b_dm, bu, HID, HID);
    hipLaunchKernelGGL(concat2, dim3(2), dim3(256), 0, stream, b_di, b_um, bd, HID, HID);

    // ---- CSR build (overlaps nothing, cheap) ----
    hipMemsetAsync(cnt_u, 0, (size_t)U * sizeof(int), stream);
    hipMemsetAsync(cnt_d, 0, (size_t)D * sizeof(int), stream);
    int egrid = (E + 255) / 256;
    hipLaunchKernelGGL(hist_kernel, dim3(egrid), dim3(256), 0, stream, edge_user, cnt_u, E);
    hipLaunchKernelGGL(hist_kernel, dim3(egrid), dim3(256), 0, stream, edge_dish, cnt_d, E);
    hipLaunchKernelGGL(scan_kernel, dim3(1), dim3(1024), 0, stream, cnt_u, offs_u, U);
    hipLaunchKernelGGL(scan_kernel, dim3(1), dim3(1024), 0, stream, cnt_d, offs_d, D);
    hipLaunchKernelGGL(fill_kernel, dim3(egrid), dim3(256), 0, stream,
                       edge_user, edge_dish, offs_u, srcl_u, E);
    hipLaunchKernelGGL(fill_kernel, dim3(egrid), dim3(256), 0, stream,
                       edge_dish, edge_user, offs_d, srcl_d, E);

    // ---- big fused projections: feat @ [Wi ‖ Wm], N=512 ----
    hipLaunchKernelGGL((mfma_gemm<true, true, false>),
                       dim3(512 / 128, (U + 127) / 128), dim3(256), 0, stream,
                       user_feat, D_IN, Wut, bu, user_buf, U, 512, D_IN);
    hipLaunchKernelGGL((mfma_gemm<true, true, false>),
                       dim3(512 / 128, (D + 127) / 128), dim3(256), 0, stream,
                       dish_feat, D_IN, Wdt, bd, dish_buf, D, 512, D_IN);

    // ---- aggregation: acc cols 0..255 += sum of msg cols 256..511 (gathered) ----
    hipLaunchKernelGGL(seg_sum_bf16, dim3((U + 3) / 4), dim3(256), 0, stream,
                       dish_buf + HID, 512, srcl_u, offs_u, cnt_u, user_buf, 512, U);
    hipLaunchKernelGGL(seg_sum_bf16, dim3((D + 3) / 4), dim3(256), 0, stream,
                       user_buf + HID, 512, srcl_d, offs_d, cnt_d, dish_buf, 512, D);

    // ---- update: relu((agg+init) @ W_uu + b), A = buf cols 0..255 (lda=512) ----
    hipLaunchKernelGGL((mfma_gemm<true, false, false>),
                       dim3(HID / 128, (U + 127) / 128), dim3(256), 0, stream,
                       user_buf, 512, Wuut, b_uu, user_upd, U, HID, HID);
    hipLaunchKernelGGL((mfma_gemm<true, false, false>),
                       dim3(HID / 128, (D + 127) / 128), dim3(256), 0, stream,
                       dish_buf, 512, Wdut, b_du, dish_upd, D, HID, HID);

    // ---- final projections: f32 output to d_out ----
    hipLaunchKernelGGL((mfma_gemm<false, false, true>),
                       dim3(OUT_D / 128, (U + 127) / 128), dim3(256), 0, stream,
                       user_upd, HID, Wupt, b_up, user_emb, U, OUT_D, HID);
    hipLaunchKernelGGL((mfma_gemm<false, false, true>),
                       dim3(OUT_D / 128, (D + 127) / 128), dim3(256), 0, stream,
                       dish_upd, HID, Wdpt, b_dp, dish_emb, D, OUT_D, HID);
}

// Round 4
// 481.953 us; speedup vs baseline: 5.4740x; 1.3969x over previous
//
#include <hip/hip_runtime.h>
#include <hip/hip_bf16.h>

// Problem dims
#define D_IN  1024
#define HID   256
#define OUT_D 128

using bf16x8  = __attribute__((ext_vector_type(8))) short;
using bf16x4  = __attribute__((ext_vector_type(4))) short;
using f32x4   = __attribute__((ext_vector_type(4))) float;
typedef unsigned int u32;

__device__ inline float bf2f(short s) {
    unsigned u = ((unsigned)(unsigned short)s) << 16;
    return __uint_as_float(u);
}
__device__ inline short f2bf(float f) {
    __hip_bfloat16 h = __float2bfloat16(f);   // RNE
    return *reinterpret_cast<short*>(&h);
}

// async global->LDS, 16 B per lane (HW: wave-uniform LDS base + lane*16)
__device__ __forceinline__ void gld16(void* lds, const void* g) {
    __builtin_amdgcn_global_load_lds(
        (const __attribute__((address_space(1))) u32*)g,
        (__attribute__((address_space(3))) u32*)lds, 16, 0, 0);
}

// ---------------------------------------------------------------------------
// f32 -> bf16 conversion (vectorized, grid-stride). n4 = element count / 4.
// ---------------------------------------------------------------------------
__global__ __launch_bounds__(256) void cvt_f32_bf16(
    const float* __restrict__ in, short* __restrict__ out, long n4)
{
    long i = blockIdx.x * (long)blockDim.x + threadIdx.x;
    long stride = (long)gridDim.x * blockDim.x;
    for (; i < n4; i += stride) {
        float4 v = reinterpret_cast<const float4*>(in)[i];
        bf16x4 s;
        s[0] = f2bf(v.x); s[1] = f2bf(v.y); s[2] = f2bf(v.z); s[3] = f2bf(v.w);
        reinterpret_cast<bf16x4*>(out)[i] = s;
    }
}

// ---------------------------------------------------------------------------
// Weight pack: f32 [K][N] -> bf16 [n_off+n][K]
// ---------------------------------------------------------------------------
__global__ void transpose_pack(const float* __restrict__ in, short* __restrict__ out,
                               int K, int N, int n_off)
{
    __shared__ float t[32][33];
    const int n0 = blockIdx.x * 32, k0 = blockIdx.y * 32;
    const int tx = threadIdx.x, ty = threadIdx.y;
#pragma unroll
    for (int j = 0; j < 32; j += 8)
        t[ty + j][tx] = in[(size_t)(k0 + ty + j) * N + (n0 + tx)];
    __syncthreads();
#pragma unroll
    for (int j = 0; j < 32; j += 8)
        out[(size_t)(n_off + n0 + ty + j) * K + (k0 + tx)] = f2bf(t[tx][ty + j]);
}

__global__ void concat2(const float* __restrict__ a, const float* __restrict__ b,
                        float* __restrict__ out, int na, int nb)
{
    int i = blockIdx.x * blockDim.x + threadIdx.x;
    if (i < na) out[i] = a[i];
    else if (i < na + nb) out[i] = b[i - na];
}

// ---------------------------------------------------------------------------
// MFMA GEMM, m97-style: C[M,N] = (relu?)(A[M,K] @ Wt^T + bias)
//   A bf16 [M][lda], Wt bf16 [N][K]. BM=BN=128, BK=64, 256 thr (4 waves 2x2),
//   wave tile 64x64 = 4x4 frags of v_mfma_f32_16x16x32_bf16.
//   Staging: global_load_lds dwordx4, linear LDS dest, XOR-swizzled SOURCE;
//   ds_read_b128 with the matching swizzle (byte c ^= (row&7)<<4, involution).
//   1-D grid with bijective XCD chunk swizzle (n fastest => A-panel siblings
//   share an XCD L2).
// ---------------------------------------------------------------------------
template <bool RELU, bool CF32>
__global__ __launch_bounds__(256) void mfma_gemm_bf16(
    const short* __restrict__ A, int lda,
    const short* __restrict__ Wt,
    const float* __restrict__ bias,
    void* __restrict__ Cvoid, int M, int N, int K, int nN)
{
    __shared__ __align__(16) short As[128 * 64];
    __shared__ __align__(16) short Bs[128 * 64];

    const int tid = threadIdx.x;

    // bijective XCD chunk swizzle (m204)
    const int nwg = gridDim.x;
    const int orig = blockIdx.x;
    const int qq = nwg >> 3, rr = nwg & 7;
    const int xcd = orig & 7, pos = orig >> 3;
    const int wg = (xcd < rr) ? (xcd * (qq + 1) + pos)
                              : (rr * (qq + 1) + (xcd - rr) * qq + pos);
    const int n0 = (wg % nN) * 128;
    const int m0 = (wg / nN) * 128;

    const int w = tid >> 6, l = tid & 63;
    const int wm = (w >> 1) * 64, wn = (w & 1) * 64;
    const int fr = l & 15, fg = l >> 4;

    f32x4 acc[4][4] = {};

    const char* Abase = (const char*)A;
    const char* Bbase = (const char*)Wt;
    const size_t lda_b = (size_t)lda * 2;
    const size_t ldb_b = (size_t)K * 2;

    for (int k0 = 0; k0 < K; k0 += 64) {
        // stage A (128 rows x 128 B) and B: 4 gld16 each
#pragma unroll
        for (int i = 0; i < 4; ++i) {
            int o = i * 4096 + tid * 16;
            int row = o >> 7, cb = o & 127;
            int scb = cb ^ ((row & 7) << 4);           // inverse-swizzled source
            int arow = m0 + row; if (arow > M - 1) arow = M - 1;  // safe clamp
            gld16((char*)As + o, Abase + (size_t)arow * lda_b + (size_t)k0 * 2 + scb);
        }
#pragma unroll
        for (int i = 0; i < 4; ++i) {
            int o = i * 4096 + tid * 16;
            int row = o >> 7, cb = o & 127;
            int scb = cb ^ ((row & 7) << 4);
            gld16((char*)Bs + o, Bbase + (size_t)(n0 + row) * ldb_b + (size_t)k0 * 2 + scb);
        }
        __syncthreads();   // compiler emits vmcnt(0) drain before barrier

#pragma unroll
        for (int kk = 0; kk < 2; ++kk) {
            bf16x8 af[4], bfv[4];
#pragma unroll
            for (int i = 0; i < 4; ++i) {
                int row = wm + i * 16 + fr;
                int cb = (kk * 64 + fg * 16) ^ ((row & 7) << 4);  // swizzled read
                af[i] = *reinterpret_cast<const bf16x8*>((const char*)As + row * 128 + cb);
            }
#pragma unroll
            for (int j = 0; j < 4; ++j) {
                int row = wn + j * 16 + fr;
                int cb = (kk * 64 + fg * 16) ^ ((row & 7) << 4);
                bfv[j] = *reinterpret_cast<const bf16x8*>((const char*)Bs + row * 128 + cb);
            }
#pragma unroll
            for (int i = 0; i < 4; ++i)
#pragma unroll
                for (int j = 0; j < 4; ++j)
                    acc[i][j] = __builtin_amdgcn_mfma_f32_16x16x32_bf16(
                        af[i], bfv[j], acc[i][j], 0, 0, 0);
        }
        __syncthreads();
    }

    // epilogue: C/D layout col=lane&15, row=(lane>>4)*4+reg  [m89-verified]
#pragma unroll
    for (int i = 0; i < 4; ++i) {
#pragma unroll
        for (int e = 0; e < 4; ++e) {
            int gm = m0 + wm + i * 16 + fg * 4 + e;
            if (gm >= M) continue;
#pragma unroll
            for (int j = 0; j < 4; ++j) {
                int gn = n0 + wn + j * 16 + fr;
                float v = acc[i][j][e] + bias[gn];
                if (RELU) v = fmaxf(v, 0.f);
                if (CF32) ((float*)Cvoid)[(size_t)gm * N + gn] = v;
                else      ((short*)Cvoid)[(size_t)gm * N + gn] = f2bf(v);
            }
        }
    }
}

// ---------------------------------------------------------------------------
// CSR construction (int atomics only)
// ---------------------------------------------------------------------------
__global__ void hist_kernel(const int* __restrict__ dst, int* __restrict__ cnt, int n)
{
    int i = blockIdx.x * blockDim.x + threadIdx.x;
    if (i < n) atomicAdd(&cnt[dst[i]], 1);
}

__global__ __launch_bounds__(1024) void scan_kernel(
    const int* __restrict__ cnt, int* __restrict__ offs, int n)
{
    __shared__ int tsum[1024];
    const int t = threadIdx.x;
    const int chunk = (n + 1023) / 1024;
    const int lo = t * chunk;
    const int hi = min(lo + chunk, n);
    int s = 0;
    for (int i = lo; i < hi; ++i) s += cnt[i];
    tsum[t] = s;
    __syncthreads();
    for (int d = 1; d < 1024; d <<= 1) {
        int v = (t >= d) ? tsum[t - d] : 0;
        __syncthreads();
        tsum[t] += v;
        __syncthreads();
    }
    int run = (t > 0) ? tsum[t - 1] : 0;
    for (int i = lo; i < hi; ++i) {
        offs[i] = run;
        run += cnt[i];
    }
}

__global__ void fill_kernel(const int* __restrict__ dst, const int* __restrict__ src,
                            int* __restrict__ offs, int* __restrict__ srclist, int n)
{
    int i = blockIdx.x * blockDim.x + threadIdx.x;
    if (i < n) {
        int p = atomicAdd(&offs[dst[i]], 1);
        srclist[p] = src[i];
    }
}

// ---------------------------------------------------------------------------
// Segment sum (bf16), one 64-lane wave per row
// ---------------------------------------------------------------------------
__global__ __launch_bounds__(256) void seg_sum_bf16(
    const short* __restrict__ msg, int msg_ld,
    const int* __restrict__ srclist,
    const int* __restrict__ offs_end, const int* __restrict__ cnt,
    short* __restrict__ acc, int acc_ld, int nRows)
{
    int row = blockIdx.x * 4 + (threadIdx.x >> 6);
    if (row >= nRows) return;
    const int lane = threadIdx.x & 63;
    const int deg = cnt[row];
    if (deg == 0) return;
    const int base = offs_end[row] - deg;

    float s0 = 0.f, s1 = 0.f, s2 = 0.f, s3 = 0.f;
    for (int j = 0; j < deg; ++j) {
        int src = srclist[base + j];
        bf16x4 v = *(const bf16x4*)&msg[(size_t)src * msg_ld + lane * 4];
        s0 += bf2f(v[0]); s1 += bf2f(v[1]); s2 += bf2f(v[2]); s3 += bf2f(v[3]);
    }
    bf16x4 c = *(bf16x4*)&acc[(size_t)row * acc_ld + lane * 4];
    c[0] = f2bf(bf2f(c[0]) + s0);
    c[1] = f2bf(bf2f(c[1]) + s1);
    c[2] = f2bf(bf2f(c[2]) + s2);
    c[3] = f2bf(bf2f(c[3]) + s3);
    *(bf16x4*)&acc[(size_t)row * acc_ld + lane * 4] = c;
}

extern "C" void kernel_launch(void* const* d_in, const int* in_sizes, int n_in,
                              void* d_out, int out_size, void* d_ws, size_t ws_size,
                              hipStream_t stream)
{
    const float* user_feat = (const float*)d_in[0];
    const float* dish_feat = (const float*)d_in[1];
    const int*   edge_user = (const int*)d_in[2];
    const int*   edge_dish = (const int*)d_in[3];
    const float* W_ui = (const float*)d_in[4];  const float* b_ui = (const float*)d_in[5];
    const float* W_di = (const float*)d_in[6];  const float* b_di = (const float*)d_in[7];
    const float* W_um = (const float*)d_in[8];  const float* b_um = (const float*)d_in[9];
    const float* W_dm = (const float*)d_in[10]; const float* b_dm = (const float*)d_in[11];
    const float* W_uu = (const float*)d_in[12]; const float* b_uu = (const float*)d_in[13];
    const float* W_du = (const float*)d_in[14]; const float* b_du = (const float*)d_in[15];
    const float* W_up = (const float*)d_in[16]; const float* b_up = (const float*)d_in[17];
    const float* W_dp = (const float*)d_in[18]; const float* b_dp = (const float*)d_in[19];

    const int U = in_sizes[0] / D_IN;   // 50000
    const int D = in_sizes[1] / D_IN;   // 10000
    const int E = in_sizes[2];          // 200000
    const int UH = U / 2;               // 25000 (user chunk rows)

    float* out = (float*)d_out;
    float* user_emb = out;
    float* dish_emb = out + (size_t)U * OUT_D;

    // ---- workspace layout (shorts). feat16 region is reused as upd buffers ----
    short* sws = (short*)d_ws;
    short* feat16   = sws;                                  // [25.6M] rotating bf16 feats
    short* user_upd = sws;                                  // alias: [U*256]
    short* dish_upd = sws + (size_t)U * 256;                // alias: [D*256] (fits in feat16)
    short* user_buf = sws + (size_t)UH * D_IN;              // [U][512]: init | msg
    short* dish_buf = user_buf + (size_t)U * 512;           // [D][512]
    short* Wut  = dish_buf + (size_t)D * 512;               // [512][1024]
    short* Wdt  = Wut  + (size_t)512 * 1024;                // [512][1024]
    short* Wuut = Wdt  + (size_t)512 * 1024;                // [256][256]
    short* Wdut = Wuut + (size_t)256 * 256;                 // [256][256]
    short* Wupt = Wdut + (size_t)256 * 256;                 // [128][256]
    short* Wdpt = Wupt + (size_t)128 * 256;                 // [128][256]
    float* bu   = (float*)(Wdpt + (size_t)128 * 256);       // [512]
    float* bd   = bu + 512;                                 // [512]
    int*   cnt_u  = (int*)(bd + 512);
    int*   offs_u = cnt_u + U;
    int*   cnt_d  = offs_u + U;
    int*   offs_d = cnt_d + D;
    int*   srcl_u = offs_d + D;                             // [E]
    int*   srcl_d = srcl_u + E;                             // [E]

    // ---- pack weights + biases ----
    dim3 tb(32, 8);
    hipLaunchKernelGGL(transpose_pack, dim3(HID / 32, D_IN / 32), tb, 0, stream,
                       W_ui, Wut, D_IN, HID, 0);
    hipLaunchKernelGGL(transpose_pack, dim3(HID / 32, D_IN / 32), tb, 0, stream,
                       W_dm, Wut, D_IN, HID, HID);
    hipLaunchKernelGGL(transpose_pack, dim3(HID / 32, D_IN / 32), tb, 0, stream,
                       W_di, Wdt, D_IN, HID, 0);
    hipLaunchKernelGGL(transpose_pack, dim3(HID / 32, D_IN / 32), tb, 0, stream,
                       W_um, Wdt, D_IN, HID, HID);
    hipLaunchKernelGGL(transpose_pack, dim3(HID / 32, HID / 32), tb, 0, stream,
                       W_uu, Wuut, HID, HID, 0);
    hipLaunchKernelGGL(transpose_pack, dim3(HID / 32, HID / 32), tb, 0, stream,
                       W_du, Wdut, HID, HID, 0);
    hipLaunchKernelGGL(transpose_pack, dim3(OUT_D / 32, HID / 32), tb, 0, stream,
                       W_up, Wupt, HID, OUT_D, 0);
    hipLaunchKernelGGL(transpose_pack, dim3(OUT_D / 32, HID / 32), tb, 0, stream,
                       W_dp, Wdpt, HID, OUT_D, 0);
    hipLaunchKernelGGL(concat2, dim3(2), dim3(256), 0, stream, b_ui, b_dm, bu, HID, HID);
    hipLaunchKernelGGL(concat2, dim3(2), dim3(256), 0, stream, b_di, b_um, bd, HID, HID);

    // ---- CSR build ----
    hipMemsetAsync(cnt_u, 0, (size_t)U * sizeof(int), stream);
    hipMemsetAsync(cnt_d, 0, (size_t)D * sizeof(int), stream);
    int egrid = (E + 255) / 256;
    hipLaunchKernelGGL(hist_kernel, dim3(egrid), dim3(256), 0, stream, edge_user, cnt_u, E);
    hipLaunchKernelGGL(hist_kernel, dim3(egrid), dim3(256), 0, stream, edge_dish, cnt_d, E);
    hipLaunchKernelGGL(scan_kernel, dim3(1), dim3(1024), 0, stream, cnt_u, offs_u, U);
    hipLaunchKernelGGL(scan_kernel, dim3(1), dim3(1024), 0, stream, cnt_d, offs_d, D);
    hipLaunchKernelGGL(fill_kernel, dim3(egrid), dim3(256), 0, stream,
                       edge_user, edge_dish, offs_u, srcl_u, E);
    hipLaunchKernelGGL(fill_kernel, dim3(egrid), dim3(256), 0, stream,
                       edge_dish, edge_user, offs_d, srcl_d, E);

    // ---- big fused projections, chunked through the rotating bf16 buffer ----
    // user rows [0, UH)
    hipLaunchKernelGGL(cvt_f32_bf16, dim3(2048), dim3(256), 0, stream,
                       user_feat, feat16, (long)UH * D_IN / 4);
    hipLaunchKernelGGL((mfma_gemm_bf16<true, false>),
                       dim3(((UH + 127) / 128) * 4), dim3(256), 0, stream,
                       feat16, D_IN, Wut, bu, user_buf, UH, 512, D_IN, 4);
    // user rows [UH, U)
    hipLaunchKernelGGL(cvt_f32_bf16, dim3(2048), dim3(256), 0, stream,
                       user_feat + (size_t)UH * D_IN, feat16, (long)(U - UH) * D_IN / 4);
    hipLaunchKernelGGL((mfma_gemm_bf16<true, false>),
                       dim3(((U - UH + 127) / 128) * 4), dim3(256), 0, stream,
                       feat16, D_IN, Wut, bu, user_buf + (size_t)UH * 512, U - UH, 512, D_IN, 4);
    // dish
    hipLaunchKernelGGL(cvt_f32_bf16, dim3(2048), dim3(256), 0, stream,
                       dish_feat, feat16, (long)D * D_IN / 4);
    hipLaunchKernelGGL((mfma_gemm_bf16<true, false>),
                       dim3(((D + 127) / 128) * 4), dim3(256), 0, stream,
                       feat16, D_IN, Wdt, bd, dish_buf, D, 512, D_IN, 4);

    // ---- aggregation (acc cols 0..255 += gathered msg cols 256..511) ----
    hipLaunchKernelGGL(seg_sum_bf16, dim3((U + 3) / 4), dim3(256), 0, stream,
                       dish_buf + HID, 512, srcl_u, offs_u, cnt_u, user_buf, 512, U);
    hipLaunchKernelGGL(seg_sum_bf16, dim3((D + 3) / 4), dim3(256), 0, stream,
                       user_buf + HID, 512, srcl_d, offs_d, cnt_d, dish_buf, 512, D);

    // ---- updates (feat16 region is dead now; upd buffers alias it) ----
    hipLaunchKernelGGL((mfma_gemm_bf16<true, false>),
                       dim3(((U + 127) / 128) * 2), dim3(256), 0, stream,
                       user_buf, 512, Wuut, b_uu, user_upd, U, HID, HID, 2);
    hipLaunchKernelGGL((mfma_gemm_bf16<true, false>),
                       dim3(((D + 127) / 128) * 2), dim3(256), 0, stream,
                       dish_buf, 512, Wdut, b_du, dish_upd, D, HID, HID, 2);

    // ---- final projections (f32 out) ----
    hipLaunchKernelGGL((mfma_gemm_bf16<false, true>),
                       dim3((U + 127) / 128), dim3(256), 0, stream,
                       user_upd, HID, Wupt, b_up, user_emb, U, OUT_D, HID, 1);
    hipLaunchKernelGGL((mfma_gemm_bf16<false, true>),
                       dim3((D + 127) / 128), dim3(256), 0, stream,
                       dish_upd, HID, Wdpt, b_dp, dish_emb, D, OUT_D, HID, 1);
}

// Round 5
// 372.252 us; speedup vs baseline: 7.0872x; 1.2947x over previous
//
#include <hip/hip_runtime.h>
#include <hip/hip_bf16.h>

// Problem dims
#define D_IN  1024
#define HID   256
#define OUT_D 128

using bf16x8  = __attribute__((ext_vector_type(8))) short;
using bf16x4  = __attribute__((ext_vector_type(4))) short;
using f32x4   = __attribute__((ext_vector_type(4))) float;
typedef unsigned int u32;

__device__ inline float bf2f(short s) {
    unsigned u = ((unsigned)(unsigned short)s) << 16;
    return __uint_as_float(u);
}
__device__ inline short f2bf(float f) {
    __hip_bfloat16 h = __float2bfloat16(f);   // RNE
    return *reinterpret_cast<short*>(&h);
}

// async global->LDS, 16 B per lane (HW: wave-uniform LDS base + lane*16)
__device__ __forceinline__ void gld16(void* lds, const void* g) {
    __builtin_amdgcn_global_load_lds(
        (const __attribute__((address_space(1))) u32*)g,
        (__attribute__((address_space(3))) u32*)lds, 16, 0, 0);
}

// ---------------------------------------------------------------------------
// pack_all: all 8 weight transposes (f32 [K][N] -> bf16 [n][K]) + bias concat
// in ONE launch. grid (8, 32, 9), block (32, 8).
// ---------------------------------------------------------------------------
__global__ void pack_all(
    const float* __restrict__ W_ui, const float* __restrict__ W_dm,
    const float* __restrict__ W_di, const float* __restrict__ W_um,
    const float* __restrict__ W_uu, const float* __restrict__ W_du,
    const float* __restrict__ W_up, const float* __restrict__ W_dp,
    const float* __restrict__ b_ui, const float* __restrict__ b_dm,
    const float* __restrict__ b_di, const float* __restrict__ b_um,
    short* __restrict__ Wut, short* __restrict__ Wdt,
    short* __restrict__ Wuut, short* __restrict__ Wdut,
    short* __restrict__ Wupt, short* __restrict__ Wdpt,
    float* __restrict__ bu, float* __restrict__ bd)
{
    const int z = blockIdx.z;
    const int tx = threadIdx.x, ty = threadIdx.y;
    if (z == 8) {  // biases
        if (blockIdx.x != 0 || blockIdx.y != 0) return;
        int t = ty * 32 + tx;  // 0..255
        bu[t] = b_ui[t]; bu[256 + t] = b_dm[t];
        bd[t] = b_di[t]; bd[256 + t] = b_um[t];
        return;
    }
    const float* in; short* out; int K, N, n_off = 0;
    switch (z) {
        case 0: in = W_ui; out = Wut;  K = 1024; N = 256; n_off = 0;   break;
        case 1: in = W_dm; out = Wut;  K = 1024; N = 256; n_off = 256; break;
        case 2: in = W_di; out = Wdt;  K = 1024; N = 256; n_off = 0;   break;
        case 3: in = W_um; out = Wdt;  K = 1024; N = 256; n_off = 256; break;
        case 4: in = W_uu; out = Wuut; K = 256;  N = 256; break;
        case 5: in = W_du; out = Wdut; K = 256;  N = 256; break;
        case 6: in = W_up; out = Wupt; K = 256;  N = 128; break;
        default:in = W_dp; out = Wdpt; K = 256;  N = 128; break;
    }
    const int n0 = blockIdx.x * 32, k0 = blockIdx.y * 32;
    if (n0 >= N || k0 >= K) return;
    __shared__ float t[32][33];
#pragma unroll
    for (int j = 0; j < 32; j += 8)
        t[ty + j][tx] = in[(size_t)(k0 + ty + j) * N + (n0 + tx)];
    __syncthreads();
#pragma unroll
    for (int j = 0; j < 32; j += 8)
        out[(size_t)(n_off + n0 + ty + j) * K + (k0 + tx)] = f2bf(t[tx][ty + j]);
}

// ---------------------------------------------------------------------------
// MFMA GEMM, m97-style. A is f32 (AF32: converted on LDS->reg read) or bf16.
// BM=BN=128, BK=64, 256 thr (4 waves 2x2), v_mfma_f32_16x16x32_bf16.
// global_load_lds staging, linear LDS dest + XOR-swizzled SOURCE (rule #21),
// matching swizzled ds_read (byte c ^= (row&7)<<4). Bijective XCD chunk
// swizzle, n-fastest (A-panel siblings share an XCD L2).
// ---------------------------------------------------------------------------
template <bool RELU, bool AF32, bool CF32>
__global__ __launch_bounds__(256) void mfma_gemm_bf16(
    const void* __restrict__ A, int lda,
    const short* __restrict__ Wt,
    const float* __restrict__ bias,
    void* __restrict__ Cvoid, int M, int N, int K, int nN)
{
    constexpr int ABYTES = AF32 ? 32768 : 16384;
    __shared__ __align__(16) char smem[ABYTES + 16384];
    char* AsB = smem;
    char* BsB = smem + ABYTES;

    const int tid = threadIdx.x;

    // bijective XCD chunk swizzle (m204)
    const int nwg = gridDim.x;
    const int orig = blockIdx.x;
    const int qq = nwg >> 3, rr = nwg & 7;
    const int xcd = orig & 7, pos = orig >> 3;
    const int wg = (xcd < rr) ? (xcd * (qq + 1) + pos)
                              : (rr * (qq + 1) + (xcd - rr) * qq + pos);
    const int n0 = (wg % nN) * 128;
    const int m0 = (wg / nN) * 128;

    const int w = tid >> 6, l = tid & 63;
    const int wm = (w >> 1) * 64, wn = (w & 1) * 64;
    const int fr = l & 15, fg = l >> 4;

    f32x4 acc[4][4] = {};

    const char* Abase = (const char*)A;
    const char* Bbase = (const char*)Wt;
    const size_t lda_b = (size_t)lda * (AF32 ? 4 : 2);
    const size_t ldb_b = (size_t)K * 2;

    for (int k0 = 0; k0 < K; k0 += 64) {
        // ---- stage A ----
        if (AF32) {
#pragma unroll
            for (int i = 0; i < 8; ++i) {   // 128 rows x 256 B
                int o = i * 4096 + tid * 16;
                int row = o >> 8, cb = o & 255;
                int scb = cb ^ ((row & 7) << 4);
                int arow = m0 + row; if (arow > M - 1) arow = M - 1;
                gld16(AsB + o, Abase + (size_t)arow * lda_b + (size_t)k0 * 4 + scb);
            }
        } else {
#pragma unroll
            for (int i = 0; i < 4; ++i) {   // 128 rows x 128 B
                int o = i * 4096 + tid * 16;
                int row = o >> 7, cb = o & 127;
                int scb = cb ^ ((row & 7) << 4);
                int arow = m0 + row; if (arow > M - 1) arow = M - 1;
                gld16(AsB + o, Abase + (size_t)arow * lda_b + (size_t)k0 * 2 + scb);
            }
        }
        // ---- stage B (bf16 weights) ----
#pragma unroll
        for (int i = 0; i < 4; ++i) {
            int o = i * 4096 + tid * 16;
            int row = o >> 7, cb = o & 127;
            int scb = cb ^ ((row & 7) << 4);
            gld16(BsB + o, Bbase + (size_t)(n0 + row) * ldb_b + (size_t)k0 * 2 + scb);
        }
        __syncthreads();   // compiler drains vmcnt before barrier

#pragma unroll
        for (int kk = 0; kk < 2; ++kk) {
            bf16x8 af[4], bfv[4];
#pragma unroll
            for (int i = 0; i < 4; ++i) {
                int row = wm + i * 16 + fr;
                if (AF32) {
                    int cbase = kk * 128 + fg * 32;
                    int c1 = cbase ^ ((row & 7) << 4);
                    int c2 = (cbase + 16) ^ ((row & 7) << 4);
                    const char* rb = AsB + row * 256;
                    f32x4 lo = *reinterpret_cast<const f32x4*>(rb + c1);
                    f32x4 hi = *reinterpret_cast<const f32x4*>(rb + c2);
                    bf16x8 t;
                    t[0] = f2bf(lo[0]); t[1] = f2bf(lo[1]);
                    t[2] = f2bf(lo[2]); t[3] = f2bf(lo[3]);
                    t[4] = f2bf(hi[0]); t[5] = f2bf(hi[1]);
                    t[6] = f2bf(hi[2]); t[7] = f2bf(hi[3]);
                    af[i] = t;
                } else {
                    int cb = (kk * 64 + fg * 16) ^ ((row & 7) << 4);
                    af[i] = *reinterpret_cast<const bf16x8*>(AsB + row * 128 + cb);
                }
            }
#pragma unroll
            for (int j = 0; j < 4; ++j) {
                int row = wn + j * 16 + fr;
                int cb = (kk * 64 + fg * 16) ^ ((row & 7) << 4);
                bfv[j] = *reinterpret_cast<const bf16x8*>(BsB + row * 128 + cb);
            }
#pragma unroll
            for (int i = 0; i < 4; ++i)
#pragma unroll
                for (int j = 0; j < 4; ++j)
                    acc[i][j] = __builtin_amdgcn_mfma_f32_16x16x32_bf16(
                        af[i], bfv[j], acc[i][j], 0, 0, 0);
        }
        __syncthreads();
    }

    // epilogue: C/D layout col=lane&15, row=(lane>>4)*4+reg  [m89-verified]
#pragma unroll
    for (int i = 0; i < 4; ++i) {
#pragma unroll
        for (int e = 0; e < 4; ++e) {
            int gm = m0 + wm + i * 16 + fg * 4 + e;
            if (gm >= M) continue;
#pragma unroll
            for (int j = 0; j < 4; ++j) {
                int gn = n0 + wn + j * 16 + fr;
                float v = acc[i][j][e] + bias[gn];
                if (RELU) v = fmaxf(v, 0.f);
                if (CF32) ((float*)Cvoid)[(size_t)gm * N + gn] = v;
                else      ((short*)Cvoid)[(size_t)gm * N + gn] = f2bf(v);
            }
        }
    }
}

// ---------------------------------------------------------------------------
// CSR construction, fused: one hist, one scan (2 blocks), one fill
// ---------------------------------------------------------------------------
__global__ void hist2(const int* __restrict__ eu, const int* __restrict__ ed,
                      int* __restrict__ cu, int* __restrict__ cd, int E)
{
    int i = blockIdx.x * blockDim.x + threadIdx.x;
    if (i < E) atomicAdd(&cu[eu[i]], 1);
    else if (i < 2 * E) atomicAdd(&cd[ed[i - E]], 1);
}

__global__ __launch_bounds__(1024) void scan2(
    const int* __restrict__ cnt_u, int* __restrict__ offs_u, int U,
    const int* __restrict__ cnt_d, int* __restrict__ offs_d, int D)
{
    const int* cnt = (blockIdx.x == 0) ? cnt_u : cnt_d;
    int* offs      = (blockIdx.x == 0) ? offs_u : offs_d;
    const int n    = (blockIdx.x == 0) ? U : D;

    __shared__ int tsum[1024];
    const int t = threadIdx.x;
    const int chunk = (n + 1023) / 1024;
    const int lo = t * chunk;
    const int hi = min(lo + chunk, n);
    int s = 0;
    for (int i = lo; i < hi; ++i) s += cnt[i];
    tsum[t] = s;
    __syncthreads();
    for (int d = 1; d < 1024; d <<= 1) {
        int v = (t >= d) ? tsum[t - d] : 0;
        __syncthreads();
        tsum[t] += v;
        __syncthreads();
    }
    int run = (t > 0) ? tsum[t - 1] : 0;
    for (int i = lo; i < hi; ++i) {
        offs[i] = run;
        run += cnt[i];
    }
}

// mutates offs -> segment END; srclist grouped by dst
__global__ void fill2(const int* __restrict__ eu, const int* __restrict__ ed,
                      int* __restrict__ offs_u, int* __restrict__ srcl_u,
                      int* __restrict__ offs_d, int* __restrict__ srcl_d, int E)
{
    int i = blockIdx.x * blockDim.x + threadIdx.x;
    if (i < E) {
        int p = atomicAdd(&offs_u[eu[i]], 1);
        srcl_u[p] = ed[i];
    } else if (i < 2 * E) {
        int k = i - E;
        int p = atomicAdd(&offs_d[ed[k]], 1);
        srcl_d[p] = eu[k];
    }
}

// ---------------------------------------------------------------------------
// Segment sum, both directions in one launch; 1 wave/row, 4-deep gather unroll
// ---------------------------------------------------------------------------
__global__ __launch_bounds__(256) void seg_sum_both(
    const short* __restrict__ dish_msg, const short* __restrict__ user_msg,
    const int* __restrict__ srcl_u, const int* __restrict__ offs_u,
    const int* __restrict__ cnt_u,
    const int* __restrict__ srcl_d, const int* __restrict__ offs_d,
    const int* __restrict__ cnt_d,
    short* __restrict__ user_buf, short* __restrict__ dish_buf,
    int U, int D, int nbU)
{
    const short* msg; const int *sl, *oe, *ct; short* acc; int nRows, rb;
    if (blockIdx.x < nbU) {
        msg = dish_msg; sl = srcl_u; oe = offs_u; ct = cnt_u;
        acc = user_buf; nRows = U; rb = blockIdx.x;
    } else {
        msg = user_msg; sl = srcl_d; oe = offs_d; ct = cnt_d;
        acc = dish_buf; nRows = D; rb = blockIdx.x - nbU;
    }
    int row = rb * 4 + (threadIdx.x >> 6);
    if (row >= nRows) return;
    const int lane = threadIdx.x & 63;
    const int deg = ct[row];
    if (deg == 0) return;
    const int base = oe[row] - deg;

    float s0 = 0.f, s1 = 0.f, s2 = 0.f, s3 = 0.f;
    int j = 0;
    for (; j + 4 <= deg; j += 4) {
        int i0 = sl[base + j], i1 = sl[base + j + 1];
        int i2 = sl[base + j + 2], i3 = sl[base + j + 3];
        bf16x4 v0 = *(const bf16x4*)&msg[(size_t)i0 * 512 + lane * 4];
        bf16x4 v1 = *(const bf16x4*)&msg[(size_t)i1 * 512 + lane * 4];
        bf16x4 v2 = *(const bf16x4*)&msg[(size_t)i2 * 512 + lane * 4];
        bf16x4 v3 = *(const bf16x4*)&msg[(size_t)i3 * 512 + lane * 4];
        s0 += bf2f(v0[0]) + bf2f(v1[0]) + bf2f(v2[0]) + bf2f(v3[0]);
        s1 += bf2f(v0[1]) + bf2f(v1[1]) + bf2f(v2[1]) + bf2f(v3[1]);
        s2 += bf2f(v0[2]) + bf2f(v1[2]) + bf2f(v2[2]) + bf2f(v3[2]);
        s3 += bf2f(v0[3]) + bf2f(v1[3]) + bf2f(v2[3]) + bf2f(v3[3]);
    }
    for (; j < deg; ++j) {
        int i0 = sl[base + j];
        bf16x4 v = *(const bf16x4*)&msg[(size_t)i0 * 512 + lane * 4];
        s0 += bf2f(v[0]); s1 += bf2f(v[1]); s2 += bf2f(v[2]); s3 += bf2f(v[3]);
    }
    bf16x4 c = *(bf16x4*)&acc[(size_t)row * 512 + lane * 4];
    c[0] = f2bf(bf2f(c[0]) + s0);
    c[1] = f2bf(bf2f(c[1]) + s1);
    c[2] = f2bf(bf2f(c[2]) + s2);
    c[3] = f2bf(bf2f(c[3]) + s3);
    *(bf16x4*)&acc[(size_t)row * 512 + lane * 4] = c;
}

extern "C" void kernel_launch(void* const* d_in, const int* in_sizes, int n_in,
                              void* d_out, int out_size, void* d_ws, size_t ws_size,
                              hipStream_t stream)
{
    const float* user_feat = (const float*)d_in[0];
    const float* dish_feat = (const float*)d_in[1];
    const int*   edge_user = (const int*)d_in[2];
    const int*   edge_dish = (const int*)d_in[3];
    const float* W_ui = (const float*)d_in[4];  const float* b_ui = (const float*)d_in[5];
    const float* W_di = (const float*)d_in[6];  const float* b_di = (const float*)d_in[7];
    const float* W_um = (const float*)d_in[8];  const float* b_um = (const float*)d_in[9];
    const float* W_dm = (const float*)d_in[10]; const float* b_dm = (const float*)d_in[11];
    const float* W_uu = (const float*)d_in[12]; const float* b_uu = (const float*)d_in[13];
    const float* W_du = (const float*)d_in[14]; const float* b_du = (const float*)d_in[15];
    const float* W_up = (const float*)d_in[16]; const float* b_up = (const float*)d_in[17];
    const float* W_dp = (const float*)d_in[18]; const float* b_dp = (const float*)d_in[19];

    const int U = in_sizes[0] / D_IN;   // 50000
    const int D = in_sizes[1] / D_IN;   // 10000
    const int E = in_sizes[2];          // 200000

    float* out = (float*)d_out;
    float* user_emb = out;
    float* dish_emb = out + (size_t)U * OUT_D;

    // ---- workspace layout (shorts) ----
    short* sws = (short*)d_ws;
    short* user_buf = sws;                                  // [U][512]: init | msg
    short* dish_buf = user_buf + (size_t)U * 512;           // [D][512]
    short* user_upd = dish_buf + (size_t)D * 512;           // [U][256]
    short* dish_upd = user_upd + (size_t)U * 256;           // [D][256]
    short* Wut  = dish_upd + (size_t)D * 256;               // [512][1024]
    short* Wdt  = Wut  + (size_t)512 * 1024;                // [512][1024]
    short* Wuut = Wdt  + (size_t)512 * 1024;                // [256][256]
    short* Wdut = Wuut + (size_t)256 * 256;                 // [256][256]
    short* Wupt = Wdut + (size_t)256 * 256;                 // [128][256]
    short* Wdpt = Wupt + (size_t)128 * 256;                 // [128][256]
    float* bu   = (float*)(Wdpt + (size_t)128 * 256);       // [512]
    float* bd   = bu + 512;                                 // [512]
    int*   cnt_u  = (int*)(bd + 512);                       // [U]  \ contiguous for
    int*   cnt_d  = cnt_u + U;                              // [D]  / single memset
    int*   offs_u = cnt_d + D;                              // [U]
    int*   offs_d = offs_u + U;                             // [D]
    int*   srcl_u = offs_d + D;                             // [E]
    int*   srcl_d = srcl_u + E;                             // [E]

    // ---- 1: pack all weights + biases ----
    hipLaunchKernelGGL(pack_all, dim3(8, 32, 9), dim3(32, 8), 0, stream,
                       W_ui, W_dm, W_di, W_um, W_uu, W_du, W_up, W_dp,
                       b_ui, b_dm, b_di, b_um,
                       Wut, Wdt, Wuut, Wdut, Wupt, Wdpt, bu, bd);

    // ---- 2-5: CSR build ----
    hipMemsetAsync(cnt_u, 0, (size_t)(U + D) * sizeof(int), stream);
    int eg2 = (2 * E + 255) / 256;
    hipLaunchKernelGGL(hist2, dim3(eg2), dim3(256), 0, stream,
                       edge_user, edge_dish, cnt_u, cnt_d, E);
    hipLaunchKernelGGL(scan2, dim3(2), dim3(1024), 0, stream,
                       cnt_u, offs_u, U, cnt_d, offs_d, D);
    hipLaunchKernelGGL(fill2, dim3(eg2), dim3(256), 0, stream,
                       edge_user, edge_dish, offs_u, srcl_u, offs_d, srcl_d, E);

    // ---- 6-7: big fused projections, f32 A direct (cvt fused in staging) ----
    hipLaunchKernelGGL((mfma_gemm_bf16<true, true, false>),
                       dim3(((U + 127) / 128) * 4), dim3(256), 0, stream,
                       user_feat, D_IN, Wut, bu, user_buf, U, 512, D_IN, 4);
    hipLaunchKernelGGL((mfma_gemm_bf16<true, true, false>),
                       dim3(((D + 127) / 128) * 4), dim3(256), 0, stream,
                       dish_feat, D_IN, Wdt, bd, dish_buf, D, 512, D_IN, 4);

    // ---- 8: aggregation, both directions ----
    int nbU = (U + 3) / 4;
    hipLaunchKernelGGL(seg_sum_both, dim3(nbU + (D + 3) / 4), dim3(256), 0, stream,
                       dish_buf + HID, user_buf + HID,
                       srcl_u, offs_u, cnt_u, srcl_d, offs_d, cnt_d,
                       user_buf, dish_buf, U, D, nbU);

    // ---- 9-10: updates (bf16 A, lda=512) ----
    hipLaunchKernelGGL((mfma_gemm_bf16<true, false, false>),
                       dim3(((U + 127) / 128) * 2), dim3(256), 0, stream,
                       user_buf, 512, Wuut, b_uu, user_upd, U, HID, HID, 2);
    hipLaunchKernelGGL((mfma_gemm_bf16<true, false, false>),
                       dim3(((D + 127) / 128) * 2), dim3(256), 0, stream,
                       dish_buf, 512, Wdut, b_du, dish_upd, D, HID, HID, 2);

    // ---- 11-12: final projections (f32 out) ----
    hipLaunchKernelGGL((mfma_gemm_bf16<false, false, true>),
                       dim3((U + 127) / 128), dim3(256), 0, stream,
                       user_upd, HID, Wupt, b_up, user_emb, U, OUT_D, HID, 1);
    hipLaunchKernelGGL((mfma_gemm_bf16<false, false, true>),
                       dim3((D + 127) / 128), dim3(256), 0, stream,
                       dish_upd, HID, Wdpt, b_dp, dish_emb, D, OUT_D, HID, 1);
}